// Round 5
// baseline (1384.941 us; speedup 1.0000x reference)
//
#include <hip/hip_runtime.h>
#include <math.h>

#define BS 4
#define HH 480
#define WW 640
#define NPX (HH * WW)          // 307200
#define NC 16
#define CHN 20
#define MM 480
#define VRD 100
#define ZHD 80
#define MINZ 9
#define MAXZ 49
#define CAP 4288                // records per (b, y-bucket) per class
#define SLOTS (400 * CAP)       // 1,715,200

// d_out float offsets
#define OFF0 0                  // fp_map_pred (40000)
#define OFF1 40000              // map_pred (18432000)  [scratch until rotate writes it]
#define OFF2 18472000           // current_poses (12)
#define OFF3 18472012           // current_poses (12)
#define OFF4 18472024           // translated (18432000) [scratch until translate writes it]
// scratch layout inside OFF1..end-of-OFF4 (all dead before their overwriters run):
#define OFFSEM 40000                        // 16 * SLOTS = 27,443,200
#define OFFGEO (OFFSEM + 16 * SLOTS)        // 3 * SLOTS (px, py, pz SoA)
#define OFFRB  (OFFGEO + 3 * SLOTS)         // 2 * SLOTS (float2 rem,depth)
#define OFFMAP (OFFRB + 2 * SLOTS)          // maps scratch 4*18*100*100 = 720000
#define OFFCNT (OFFMAP + 720000)            // cntA 6400 + cntB 6400 ints

__device__ __forceinline__ void pix2pos(int w, int h, float depth, float ca, float sa,
                                        float foc, float& px, float& py, float& pz) {
    float gx = (float)w;
    float gz = (float)(HH - 1 - h);
    float Xp = (gx - 319.5f) * depth / foc;
    float Zp = (gz - 239.5f) * depth / foc;
    float Yv = ca * depth - sa * Zp;
    float Zv = sa * depth + ca * Zp + 155.0f;
    float Xv = Xp + 250.0f;
    float xs = (Xv / 5.0f - 50.0f) / 100.0f * 2.0f;
    float ys = (Yv / 5.0f - 50.0f) / 100.0f * 2.0f;
    float zs = (Zv / 5.0f - 32.0f) / 80.0f * 2.0f;
    px = xs * 50.0f + 50.0f;
    py = ys * 50.0f + 50.0f;
    pz = zs * 40.0f + 40.0f;
}

// bin + classify + pre-gather. Class A (sem-relevant, pz in [8,49)): SoA geometry
// + 16 sem values in slot order (reads coalesced here, consumed as coalesced
// streams by slice). Class B (occ-only, pz in [0,8) u [49,80)): 8B (rem,depth).
// Records that can never contribute (x-cull, z-dead, y-bucket invalid) dropped.
__global__ __launch_bounds__(256) void bin_kernel(const float* __restrict__ obs,
                                                  const float* __restrict__ va,
                                                  int* __restrict__ cntA,
                                                  int* __restrict__ cntB,
                                                  float* __restrict__ gpx,
                                                  float* __restrict__ gpy,
                                                  float* __restrict__ gpz,
                                                  float* __restrict__ sem,
                                                  float2* __restrict__ recB,
                                                  float foc) {
    int idx = blockIdx.x * blockDim.x + threadIdx.x;
    if (idx >= BS * NPX) return;
    int b   = idx / NPX;
    int rem = idx % NPX;
    float depth = obs[((size_t)b * CHN + 3) * NPX + rem];
    int h = rem / WW, w = rem % WW;
    float a  = va[b] * 0.017453292519943295f;
    float ca = cosf(a), sa = sinf(a);
    float px, py, pz;
    pix2pos(w, h, depth, ca, sa, foc, px, py, pz);
    float ff = floorf(py);
    if (!(ff >= 0.0f && ff < 100.0f)) return;
    float fx = floorf(px);
    if (!(fx + 1.0f > 0.0f && fx < 100.0f)) return;   // record-level x-cull (cell checks imply)
    int f = (int)ff;
    bool aok = (pz >= 8.0f && pz < 49.0f);
    bool bok = !aok && (pz >= 0.0f && pz < 80.0f);
    if (aok) {
        int slot = atomicAdd(cntA + (b * VRD + f) * 16, 1);
        if (slot < CAP) {
            int o = (b * VRD + f) * CAP + slot;
            gpx[o] = px; gpy[o] = py; gpz[o] = pz;
            const float* sp = obs + ((size_t)b * CHN + 4) * NPX + rem;
            #pragma unroll
            for (int c = 0; c < NC; c++) sem[(size_t)c * SLOTS + o] = sp[(size_t)c * NPX];
        }
    } else if (bok) {
        int slot = atomicAdd(cntB + (b * VRD + f) * 16, 1);
        if (slot < CAP) {
            float2 r; r.x = __int_as_float(rem); r.y = depth;
            recB[(b * VRD + f) * CAP + slot] = r;
        }
    }
}

// unified slice kernel, logical wgid = b*900 + g*100 + s (batch-major + XCD swizzle).
// g in [0,8): sem pair {2g,2g+1}: stream A-records (px,py,pz,sem0,sem1 — ALL
//   coalesced), LDS acc [z40][x100][c2] -> maps[2+2g],[3+2g]
// g == 8: occupancy: stream A geometry + B (rem,depth) records (pix2pos
//   recomputed, bit-identical), LDS acc [z80][x100] -> maps[0],[1], out0
__global__ __launch_bounds__(256, 5) void slice_kernel(const int* __restrict__ cntA,
                                                       const int* __restrict__ cntB,
                                                       const float* __restrict__ gpx,
                                                       const float* __restrict__ gpy,
                                                       const float* __restrict__ gpz,
                                                       const float* __restrict__ sem,
                                                       const float2* __restrict__ recB,
                                                       const float* __restrict__ va,
                                                       float* __restrict__ maps,
                                                       float* __restrict__ out0,
                                                       float foc) {
    __shared__ float acc[8000];   // 32 KB
    int bid  = blockIdx.x;                       // 0..3599
    int wgid = (bid & 7) * 450 + (bid >> 3);     // bijective XCD swizzle (3600 % 8 == 0)
    int b  = wgid / 900;
    int r_ = wgid % 900;
    int g  = r_ / 100;                           // 0..8
    int s  = r_ % 100;
    int tid = threadIdx.x;
    for (int i = tid; i < 8000; i += 256) acc[i] = 0.0f;
    __syncthreads();

    if (s > 0) {
        float fs = (float)s;
        int f0 = s - 1, f1 = s;
        int a0 = min(cntA[(b * VRD + f0) * 16], CAP);
        int a1 = min(cntA[(b * VRD + f1) * 16], CAP);
        int base0 = (b * VRD + f0) * CAP;
        int base1 = (b * VRD + f1) * CAP;
        int NA = a0 + a1;

        if (g < 8) {
            const float* s0p = sem + (size_t)(2 * g) * SLOTS;
            const float* s1p = sem + (size_t)(2 * g + 1) * SLOTS;
            for (int base = tid; base < NA; base += 1024) {
                int o[4]; bool vld[4];
                #pragma unroll
                for (int j = 0; j < 4; j++) {
                    int t = base + (j << 8);
                    vld[j] = (t < NA);
                    int oo = (t < a0) ? (base0 + t) : (base1 + (t - a0));
                    o[j] = vld[j] ? oo : base0;
                }
                float px[4], py[4], pz[4], v0[4], v1[4];
                #pragma unroll
                for (int j = 0; j < 4; j++) {
                    px[j] = gpx[o[j]]; py[j] = gpy[o[j]]; pz[j] = gpz[o[j]];
                    v0[j] = s0p[o[j]]; v1[j] = s1p[o[j]];
                }
                #pragma unroll
                for (int j = 0; j < 4; j++) {
                    if (!vld[j]) continue;
                    float wy = 1.0f - fabsf(py[j] - fs);
                    if (wy <= 0.0f) continue;
                    float fx = floorf(px[j]), fz = floorf(pz[j]);
                    #pragma unroll
                    for (int i2 = 0; i2 < 2; i2++) {
                        float cxp = fx + (float)i2;
                        if (!(cxp > 0.0f && cxp < 100.0f)) continue;
                        float wxy = wy * (1.0f - fabsf(px[j] - cxp));
                        int xi = (int)cxp;
                        #pragma unroll
                        for (int k = 0; k < 2; k++) {
                            float czp = fz + (float)k;
                            if (czp < 9.0f || czp >= 49.0f) continue;
                            float w3 = wxy * (1.0f - fabsf(pz[j] - czp));
                            if (w3 == 0.0f) continue;
                            float* dst = &acc[(((int)czp - MINZ) * VRD + xi) * 2];
                            atomicAdd(dst + 0, w3 * v0[j]);
                            atomicAdd(dst + 1, w3 * v1[j]);
                        }
                    }
                }
            }
        } else {
            // occupancy: A geometry stream
            for (int base = tid; base < NA; base += 1024) {
                int o[4]; bool vld[4];
                #pragma unroll
                for (int j = 0; j < 4; j++) {
                    int t = base + (j << 8);
                    vld[j] = (t < NA);
                    int oo = (t < a0) ? (base0 + t) : (base1 + (t - a0));
                    o[j] = vld[j] ? oo : base0;
                }
                float px[4], py[4], pz[4];
                #pragma unroll
                for (int j = 0; j < 4; j++) {
                    px[j] = gpx[o[j]]; py[j] = gpy[o[j]]; pz[j] = gpz[o[j]];
                }
                #pragma unroll
                for (int j = 0; j < 4; j++) {
                    if (!vld[j]) continue;
                    float wy = 1.0f - fabsf(py[j] - fs);
                    if (wy <= 0.0f) continue;
                    float fx = floorf(px[j]), fz = floorf(pz[j]);
                    #pragma unroll
                    for (int i2 = 0; i2 < 2; i2++) {
                        float cxp = fx + (float)i2;
                        if (!(cxp > 0.0f && cxp < 100.0f)) continue;
                        float wxy = wy * (1.0f - fabsf(px[j] - cxp));
                        int xi = (int)cxp;
                        #pragma unroll
                        for (int k = 0; k < 2; k++) {
                            float czp = fz + (float)k;
                            if (czp < 1.0f || czp >= 80.0f) continue;
                            float w3 = wxy * (1.0f - fabsf(pz[j] - czp));
                            if (w3 == 0.0f) continue;
                            atomicAdd(&acc[(int)czp * VRD + xi], w3);
                        }
                    }
                }
            }
            // occupancy: B (rem,depth) stream, geometry recomputed (bit-identical)
            float a_  = va[b] * 0.017453292519943295f;
            float ca = cosf(a_), sa = sinf(a_);
            int b0 = min(cntB[(b * VRD + f0) * 16], CAP);
            int b1 = min(cntB[(b * VRD + f1) * 16], CAP);
            int NB = b0 + b1;
            for (int base = tid; base < NB; base += 1024) {
                float2 rv[4]; bool vld[4];
                #pragma unroll
                for (int j = 0; j < 4; j++) {
                    int t = base + (j << 8);
                    vld[j] = (t < NB);
                    int oo = (t < b0) ? (base0 + t) : (base1 + (t - b0));
                    rv[j] = vld[j] ? recB[oo] : make_float2(0.0f, 0.0f);
                }
                #pragma unroll
                for (int j = 0; j < 4; j++) {
                    if (!vld[j]) continue;
                    int rm = __float_as_int(rv[j].x);
                    float px, py, pz;
                    pix2pos(rm % WW, rm / WW, rv[j].y, ca, sa, foc, px, py, pz);
                    float wy = 1.0f - fabsf(py - fs);
                    if (wy <= 0.0f) continue;
                    float fx = floorf(px), fz = floorf(pz);
                    #pragma unroll
                    for (int i2 = 0; i2 < 2; i2++) {
                        float cxp = fx + (float)i2;
                        if (!(cxp > 0.0f && cxp < 100.0f)) continue;
                        float wxy = wy * (1.0f - fabsf(px - cxp));
                        int xi = (int)cxp;
                        #pragma unroll
                        for (int k = 0; k < 2; k++) {
                            float czp = fz + (float)k;
                            if (czp < 1.0f || czp >= 80.0f) continue;
                            float w3 = wxy * (1.0f - fabsf(pz - czp));
                            if (w3 == 0.0f) continue;
                            atomicAdd(&acc[(int)czp * VRD + xi], w3);
                        }
                    }
                }
            }
        }
    }
    __syncthreads();

    if (g < 8) {
        for (int i = tid; i < VRD * 2; i += 256) {
            int x = i >> 1, c = i & 1;
            float ssum = 0.0f;
            #pragma unroll 8
            for (int z = 0; z < 40; z++) ssum += rintf(acc[(z * VRD + x) * 2 + c]);
            maps[((size_t)(b * 18 + 2 + 2 * g + c) * VRD + s) * VRD + x] =
                fminf(fmaxf(ssum * 0.2f, 0.0f), 1.0f);
        }
    } else {
        for (int x = tid; x < VRD; x += 256) {
            float s_all = 0.0f, s_agg = 0.0f;
            #pragma unroll 8
            for (int z = 0; z < ZHD; z++) {
                float r = rintf(acc[z * VRD + x]);
                s_all += r;
                if (z >= MINZ && z < MAXZ) s_agg += r;
            }
            float fm = fminf(fmaxf(s_agg, 0.0f), 1.0f);
            float fe = fminf(fmaxf(s_all, 0.0f), 1.0f);
            maps[((size_t)(b * 18 + 0) * VRD + s) * VRD + x] = fm;
            maps[((size_t)(b * 18 + 1) * VRD + s) * VRD + x] = fe;
            out0[((size_t)b * VRD + s) * VRD + x] = fm;
        }
    }
}

__device__ __forceinline__ void pose_params(const float* __restrict__ pose_obs,
                                            const float* __restrict__ poses_last,
                                            int b, float& ct, float& st,
                                            float& stx, float& sty) {
    const float DEG = 57.29577951308232f;
    float o  = poses_last[b*3+2] / DEG;
    float so = sinf(o), co = cosf(o);
    float yy = poses_last[b*3+1] + pose_obs[b*3+0]*so + pose_obs[b*3+1]*co;
    float xx = poses_last[b*3+0] + pose_obs[b*3+0]*co - pose_obs[b*3+1]*so;
    float tt = poses_last[b*3+2] + pose_obs[b*3+2]*DEG;
    tt = fmodf(tt - 180.0f, 360.0f) + 180.0f;
    tt = fmodf(tt + 180.0f, 360.0f) - 180.0f;
    stx = -((xx*100.0f/5.0f) - 240.0f) / 240.0f;
    sty = -((yy*100.0f/5.0f) - 240.0f) / 240.0f;
    float t = (90.0f - tt) * 0.017453292519943295f;
    ct = cosf(t); st = sinf(t);
}

__global__ __launch_bounds__(64) void pose_kernel(const float* __restrict__ pose_obs,
                                                  const float* __restrict__ poses_last,
                                                  float* __restrict__ out) {
    int b = threadIdx.x;
    if (b >= BS) return;
    const float DEG = 57.29577951308232f;
    float o  = poses_last[b*3+2] / DEG;
    float so = sinf(o), co = cosf(o);
    float yy = poses_last[b*3+1] + pose_obs[b*3+0]*so + pose_obs[b*3+1]*co;
    float xx = poses_last[b*3+0] + pose_obs[b*3+0]*co - pose_obs[b*3+1]*so;
    float tt = poses_last[b*3+2] + pose_obs[b*3+2]*DEG;
    tt = fmodf(tt - 180.0f, 360.0f) + 180.0f;
    tt = fmodf(tt + 180.0f, 360.0f) - 180.0f;
    out[OFF2 + b*3+0] = xx; out[OFF2 + b*3+1] = yy; out[OFF2 + b*3+2] = tt;
    out[OFF3 + b*3+0] = xx; out[OFF3 + b*3+1] = yy; out[OFF3 + b*3+2] = tt;
}

__global__ __launch_bounds__(256) void rotate_kernel(const float* __restrict__ maps,
                                                     const float* __restrict__ pose_obs,
                                                     const float* __restrict__ poses_last,
                                                     float* __restrict__ rot) {
    int idx = blockIdx.x * blockDim.x + threadIdx.x;
    if (idx >= BS * MM * MM) return;
    int b   = idx / (MM * MM);
    int rem = idx % (MM * MM);
    int y   = rem / MM;
    int x   = rem % MM;
    float ct, st, stx, sty;
    pose_params(pose_obs, poses_last, b, ct, st, stx, sty);
    float Xg = -1.0f + (float)x * (2.0f / 479.0f);
    float Yg = -1.0f + (float)y * (2.0f / 479.0f);
    float gx = ct * Xg - st * Yg;
    float gy = st * Xg + ct * Yg;
    float xf = (gx + 1.0f) * 0.5f * 479.0f;
    float yf = (gy + 1.0f) * 0.5f * 479.0f;
    float x0 = floorf(xf), y0 = floorf(yf);
    float fx = xf - x0, fy = yf - y0;
    float cw[4] = {(1.0f - fx) * (1.0f - fy), fx * (1.0f - fy),
                   (1.0f - fx) * fy,          fx * fy};
    float cx[4] = {x0, x0 + 1.0f, x0, x0 + 1.0f};
    float cy[4] = {y0, y0, y0 + 1.0f, y0 + 1.0f};
    float acc[18];
    #pragma unroll
    for (int m = 0; m < 18; m++) acc[m] = 0.0f;
    #pragma unroll
    for (int k = 0; k < 4; k++) {
        float fxk = cx[k], fyk = cy[k];
        if (!(fxk >= 0.0f && fxk <= 479.0f && fyk >= 0.0f && fyk <= 479.0f)) continue;
        int ix = (int)fxk, iy = (int)fyk;
        if (iy < 240 || iy >= 340 || ix < 190 || ix >= 290) continue;
        int mi = iy - 240, mj = ix - 190;
        float w = cw[k];
        const float* mp = maps + (size_t)b * 18 * VRD * VRD + mi * VRD + mj;
        #pragma unroll
        for (int m = 0; m < 18; m++) acc[m] += w * mp[(size_t)m * VRD * VRD];
    }
    size_t obase = ((size_t)b * CHN) * MM * MM + (size_t)y * MM + x;
    rot[obase + (size_t)0 * MM * MM] = acc[0];
    rot[obase + (size_t)1 * MM * MM] = acc[1];
    rot[obase + (size_t)2 * MM * MM] = 0.0f;
    rot[obase + (size_t)3 * MM * MM] = 0.0f;
    #pragma unroll
    for (int m = 2; m < 18; m++)
        rot[obase + (size_t)(m + 2) * MM * MM] = acc[m];
}

__global__ __launch_bounds__(256) void translate_kernel(const float* __restrict__ rot,
                                                        const float* __restrict__ pose_obs,
                                                        const float* __restrict__ poses_last,
                                                        float* __restrict__ tr) {
    int idx = blockIdx.x * blockDim.x + threadIdx.x;
    if (idx >= BS * MM * MM) return;
    int b   = idx / (MM * MM);
    int rem = idx % (MM * MM);
    int y   = rem / MM;
    int x   = rem % MM;
    float ct, st, stx, sty;
    pose_params(pose_obs, poses_last, b, ct, st, stx, sty);
    float Xg = -1.0f + (float)x * (2.0f / 479.0f);
    float Yg = -1.0f + (float)y * (2.0f / 479.0f);
    float xf = (Xg + stx + 1.0f) * 0.5f * 479.0f;
    float yf = (Yg + sty + 1.0f) * 0.5f * 479.0f;
    float x0 = floorf(xf), y0 = floorf(yf);
    float fx = xf - x0, fy = yf - y0;
    float cw[4] = {(1.0f - fx) * (1.0f - fy), fx * (1.0f - fy),
                   (1.0f - fx) * fy,          fx * fy};
    float cxs[4] = {x0, x0 + 1.0f, x0, x0 + 1.0f};
    float cys[4] = {y0, y0, y0 + 1.0f, y0 + 1.0f};
    bool vk[4]; int offk[4];
    #pragma unroll
    for (int k = 0; k < 4; k++) {
        vk[k] = (cxs[k] >= 0.0f && cxs[k] <= 479.0f && cys[k] >= 0.0f && cys[k] <= 479.0f);
        offk[k] = vk[k] ? ((int)cys[k] * MM + (int)cxs[k]) : 0;
    }
    #pragma unroll
    for (int c = 0; c < CHN; c++) {
        const float* rp = rot + ((size_t)b * CHN + c) * MM * MM;
        float v = 0.0f;
        #pragma unroll
        for (int k = 0; k < 4; k++)
            if (vk[k]) v += cw[k] * rp[offk[k]];
        tr[((size_t)b * CHN + c) * MM * MM + (size_t)y * MM + x] = v;
    }
}

__global__ __launch_bounds__(256) void max_kernel(const float* __restrict__ maps_last,
                                                  const float* __restrict__ tr,
                                                  float* __restrict__ mp) {
    int i = blockIdx.x * blockDim.x + threadIdx.x;
    int n4 = BS * CHN * MM * MM / 4;
    if (i >= n4) return;
    float4 a = ((const float4*)maps_last)[i];
    float4 t = ((const float4*)tr)[i];
    float4 r;
    r.x = fmaxf(a.x, t.x);
    r.y = fmaxf(a.y, t.y);
    r.z = fmaxf(a.z, t.z);
    r.w = fmaxf(a.w, t.w);
    ((float4*)mp)[i] = r;
}

extern "C" void kernel_launch(void* const* d_in, const int* in_sizes, int n_in,
                              void* d_out, int out_size, void* d_ws, size_t ws_size,
                              hipStream_t stream) {
    const float* obs         = (const float*)d_in[0];
    const float* pose_obs    = (const float*)d_in[1];
    const float* maps_last   = (const float*)d_in[2];
    const float* poses_last  = (const float*)d_in[3];
    const float* view_angles = (const float*)d_in[4];
    float* out = (float*)d_out;

    float*  sem   = out + OFFSEM;
    float*  gpx   = out + OFFGEO;
    float*  gpy   = out + OFFGEO + SLOTS;
    float*  gpz   = out + OFFGEO + 2 * SLOTS;
    float2* recB  = (float2*)(out + OFFRB);
    float*  maps  = out + OFFMAP;
    int*    cntA  = (int*)(out + OFFCNT);
    int*    cntB  = cntA + 6400;

    hipMemsetAsync(cntA, 0, 12800 * sizeof(int), stream);

    const float foc = (float)(320.0 / tan(39.5 * M_PI / 180.0));

    int npix = BS * NPX;
    bin_kernel<<<(npix + 255) / 256, 256, 0, stream>>>(obs, view_angles, cntA, cntB,
                                                       gpx, gpy, gpz, sem, recB, foc);

    // 4 batches x 9 groups (8 sem pairs + occ) x 100 slices, batch-major
    slice_kernel<<<dim3(VRD * BS * 9), 256, 0, stream>>>(cntA, cntB, gpx, gpy, gpz,
                                                         sem, recB, view_angles,
                                                         maps, out + OFF0, foc);

    pose_kernel<<<1, 64, 0, stream>>>(pose_obs, poses_last, out);

    int nmap = BS * MM * MM;
    rotate_kernel<<<(nmap + 255) / 256, 256, 0, stream>>>(maps, pose_obs, poses_last,
                                                          out + OFF1);
    translate_kernel<<<(nmap + 255) / 256, 256, 0, stream>>>(out + OFF1, pose_obs,
                                                             poses_last, out + OFF4);
    int n4 = BS * CHN * MM * MM / 4;
    max_kernel<<<(n4 + 255) / 256, 256, 0, stream>>>(maps_last, out + OFF4, out + OFF1);
}

// Round 6
// 1340.926 us; speedup vs baseline: 1.0328x; 1.0328x over previous
//
#include <hip/hip_runtime.h>
#include <math.h>

#define BS 4
#define HH 480
#define WW 640
#define NPX (HH * WW)          // 307200
#define NC 16
#define CHN 20
#define MM 480
#define VRD 100
#define ZHD 80
#define MINZ 9
#define MAXZ 49
#define CAP 4288                // records per (b, y-bucket) per class
#define SLOTS (400 * CAP)       // 1,715,200

// d_out float offsets
#define OFF0 0                  // fp_map_pred (40000)
#define OFF1 40000              // map_pred (18432000)  [scratch until rotate writes it]
#define OFF2 18472000           // current_poses (12)
#define OFF3 18472012           // current_poses (12)
#define OFF4 18472024           // translated (18432000) [scratch until translate writes it]
// scratch layout inside OFF1..end-of-OFF4 (all dead before their overwriters run):
#define OFFSEM 40000                        // 16 * SLOTS = 27,443,200
#define OFFGEO (OFFSEM + 16 * SLOTS)        // 3 * SLOTS (px, py, pz SoA)
#define OFFRB  (OFFGEO + 3 * SLOTS)         // 2 * SLOTS (float2 rem,depth)
#define OFFMAP (OFFRB + 2 * SLOTS)          // maps scratch 4*18*100*100 = 720000
#define OFFCNT (OFFMAP + 720000)            // cntA 6400 + cntB 6400 ints

__device__ __forceinline__ void pix2pos(int w, int h, float depth, float ca, float sa,
                                        float foc, float& px, float& py, float& pz) {
    float gx = (float)w;
    float gz = (float)(HH - 1 - h);
    float Xp = (gx - 319.5f) * depth / foc;
    float Zp = (gz - 239.5f) * depth / foc;
    float Yv = ca * depth - sa * Zp;
    float Zv = sa * depth + ca * Zp + 155.0f;
    float Xv = Xp + 250.0f;
    float xs = (Xv / 5.0f - 50.0f) / 100.0f * 2.0f;
    float ys = (Yv / 5.0f - 50.0f) / 100.0f * 2.0f;
    float zs = (Zv / 5.0f - 32.0f) / 80.0f * 2.0f;
    px = xs * 50.0f + 50.0f;
    py = ys * 50.0f + 50.0f;
    pz = zs * 40.0f + 40.0f;
}

// bin + classify + pre-gather. Class A (sem-relevant, pz in [8,49)): SoA geometry
// + 16 sem values in slot order. Class B (occ-only): 8B (rem,depth).
__global__ __launch_bounds__(256) void bin_kernel(const float* __restrict__ obs,
                                                  const float* __restrict__ va,
                                                  int* __restrict__ cntA,
                                                  int* __restrict__ cntB,
                                                  float* __restrict__ gpx,
                                                  float* __restrict__ gpy,
                                                  float* __restrict__ gpz,
                                                  float* __restrict__ sem,
                                                  float2* __restrict__ recB,
                                                  float foc) {
    int idx = blockIdx.x * blockDim.x + threadIdx.x;
    if (idx >= BS * NPX) return;
    int b   = idx / NPX;
    int rem = idx % NPX;
    float depth = obs[((size_t)b * CHN + 3) * NPX + rem];
    int h = rem / WW, w = rem % WW;
    float a  = va[b] * 0.017453292519943295f;
    float ca = cosf(a), sa = sinf(a);
    float px, py, pz;
    pix2pos(w, h, depth, ca, sa, foc, px, py, pz);
    float ff = floorf(py);
    if (!(ff >= 0.0f && ff < 100.0f)) return;
    float fx = floorf(px);
    if (!(fx + 1.0f > 0.0f && fx < 100.0f)) return;   // record-level x-cull
    int f = (int)ff;
    bool aok = (pz >= 8.0f && pz < 49.0f);
    bool bok = !aok && (pz >= 0.0f && pz < 80.0f);
    if (aok) {
        int slot = atomicAdd(cntA + (b * VRD + f) * 16, 1);
        if (slot < CAP) {
            int o = (b * VRD + f) * CAP + slot;
            gpx[o] = px; gpy[o] = py; gpz[o] = pz;
            const float* sp = obs + ((size_t)b * CHN + 4) * NPX + rem;
            #pragma unroll
            for (int c = 0; c < NC; c++) sem[(size_t)c * SLOTS + o] = sp[(size_t)c * NPX];
        }
    } else if (bok) {
        int slot = atomicAdd(cntB + (b * VRD + f) * 16, 1);
        if (slot < CAP) {
            float2 r; r.x = __int_as_float(rem); r.y = depth;
            recB[(b * VRD + f) * CAP + slot] = r;
        }
    }
}

// unified slice kernel, logical wgid = b*900 + g*100 + s (batch-major + XCD swizzle).
// Per-thread CONTIGUOUS slot chunks + register run-merging on (fx,fz):
// lanes are ~chunk apart -> LDS atomics from a wave hit different cells
// (no same-address serialization), and runs of equal-cell records collapse
// into one flush (8 atomics sem / 4 atomics occ per run).
__global__ __launch_bounds__(256, 5) void slice_kernel(const int* __restrict__ cntA,
                                                       const int* __restrict__ cntB,
                                                       const float* __restrict__ gpx,
                                                       const float* __restrict__ gpy,
                                                       const float* __restrict__ gpz,
                                                       const float* __restrict__ sem,
                                                       const float2* __restrict__ recB,
                                                       const float* __restrict__ va,
                                                       float* __restrict__ maps,
                                                       float* __restrict__ out0,
                                                       float foc) {
    __shared__ float acc[8000];   // 32 KB
    int bid  = blockIdx.x;                       // 0..3599
    int wgid = (bid & 7) * 450 + (bid >> 3);     // bijective XCD swizzle (3600 % 8 == 0)
    int b  = wgid / 900;
    int r_ = wgid % 900;
    int g  = r_ / 100;                           // 0..8
    int s  = r_ % 100;
    int tid = threadIdx.x;
    for (int i = tid; i < 8000; i += 256) acc[i] = 0.0f;
    __syncthreads();

    if (s > 0) {
        float fs = (float)s;
        int f0 = s - 1, f1 = s;
        int a0 = min(cntA[(b * VRD + f0) * 16], CAP);
        int a1 = min(cntA[(b * VRD + f1) * 16], CAP);
        int base0 = (b * VRD + f0) * CAP;
        int base1 = (b * VRD + f1) * CAP;
        int NA = a0 + a1;

        if (g < 8) {
            const float* s0p = sem + (size_t)(2 * g) * SLOTS;
            const float* s1p = sem + (size_t)(2 * g + 1) * SLOTS;
            int chunk = (NA + 255) >> 8;
            int beg = tid * chunk;
            int end = min(beg + chunk, NA);
            int key = -1;
            float a00c0 = 0, a00c1 = 0, a01c0 = 0, a01c1 = 0;
            float a10c0 = 0, a10c1 = 0, a11c0 = 0, a11c1 = 0;
            auto flushS = [&]() {
                if (key < 0) return;
                int ix = key >> 7, iz = key & 127;
                bool vx0 = ix > 0, vx1 = ix < 99;
                bool vz0 = iz >= 9, vz1 = iz <= 47;
                if (vx0 && vz0) { float* d = &acc[((iz - 9) * VRD + ix) * 2];
                                  atomicAdd(d, a00c0); atomicAdd(d + 1, a00c1); }
                if (vx0 && vz1) { float* d = &acc[((iz - 8) * VRD + ix) * 2];
                                  atomicAdd(d, a01c0); atomicAdd(d + 1, a01c1); }
                if (vx1 && vz0) { float* d = &acc[((iz - 9) * VRD + ix + 1) * 2];
                                  atomicAdd(d, a10c0); atomicAdd(d + 1, a10c1); }
                if (vx1 && vz1) { float* d = &acc[((iz - 8) * VRD + ix + 1) * 2];
                                  atomicAdd(d, a11c0); atomicAdd(d + 1, a11c1); }
            };
            for (int t = beg; t < end; t++) {
                int o = (t < a0) ? (base0 + t) : (base1 + (t - a0));
                float px = gpx[o], py = gpy[o], pz = gpz[o];
                float wy = 1.0f - fabsf(py - fs);
                if (wy <= 0.0f) continue;
                float fx = floorf(px), fz = floorf(pz);
                int k2 = ((int)fx << 7) | (int)fz;
                if (k2 != key) {
                    flushS();
                    key = k2;
                    a00c0 = a00c1 = a01c0 = a01c1 = 0.0f;
                    a10c0 = a10c1 = a11c0 = a11c1 = 0.0f;
                }
                float v0 = s0p[o], v1 = s1p[o];
                float wx0 = 1.0f - fabsf(px - fx);
                float wx1 = 1.0f - fabsf(px - (fx + 1.0f));
                float wz0 = 1.0f - fabsf(pz - fz);
                float wz1 = 1.0f - fabsf(pz - (fz + 1.0f));
                float wxy0 = wy * wx0, wxy1 = wy * wx1;
                float w00 = wxy0 * wz0, w01 = wxy0 * wz1;
                float w10 = wxy1 * wz0, w11 = wxy1 * wz1;
                a00c0 += w00 * v0; a00c1 += w00 * v1;
                a01c0 += w01 * v0; a01c1 += w01 * v1;
                a10c0 += w10 * v0; a10c1 += w10 * v1;
                a11c0 += w11 * v0; a11c1 += w11 * v1;
            }
            flushS();
        } else {
            // occupancy: valid z-cells [1,80)
            int key = -1;
            float a00 = 0, a01 = 0, a10 = 0, a11 = 0;
            auto flushO = [&]() {
                if (key < 0) return;
                int ix = key >> 7, iz = key & 127;
                bool vx0 = ix > 0, vx1 = ix < 99;
                bool vz0 = iz >= 1, vz1 = iz <= 78;
                if (vx0 && vz0) atomicAdd(&acc[iz * VRD + ix], a00);
                if (vx0 && vz1) atomicAdd(&acc[(iz + 1) * VRD + ix], a01);
                if (vx1 && vz0) atomicAdd(&acc[iz * VRD + ix + 1], a10);
                if (vx1 && vz1) atomicAdd(&acc[(iz + 1) * VRD + ix + 1], a11);
            };
            // stream 1: A geometry
            {
                int chunk = (NA + 255) >> 8;
                int beg = tid * chunk;
                int end = min(beg + chunk, NA);
                for (int t = beg; t < end; t++) {
                    int o = (t < a0) ? (base0 + t) : (base1 + (t - a0));
                    float px = gpx[o], py = gpy[o], pz = gpz[o];
                    float wy = 1.0f - fabsf(py - fs);
                    if (wy <= 0.0f) continue;
                    float fx = floorf(px), fz = floorf(pz);
                    int k2 = ((int)fx << 7) | (int)fz;
                    if (k2 != key) {
                        flushO();
                        key = k2;
                        a00 = a01 = a10 = a11 = 0.0f;
                    }
                    float wx0 = 1.0f - fabsf(px - fx);
                    float wx1 = 1.0f - fabsf(px - (fx + 1.0f));
                    float wz0 = 1.0f - fabsf(pz - fz);
                    float wz1 = 1.0f - fabsf(pz - (fz + 1.0f));
                    float wxy0 = wy * wx0, wxy1 = wy * wx1;
                    a00 += wxy0 * wz0; a01 += wxy0 * wz1;
                    a10 += wxy1 * wz0; a11 += wxy1 * wz1;
                }
                flushO();
                key = -1; a00 = a01 = a10 = a11 = 0.0f;
            }
            // stream 2: B (rem,depth), geometry recomputed (bit-identical)
            {
                float a_ = va[b] * 0.017453292519943295f;
                float ca = cosf(a_), sa = sinf(a_);
                int b0 = min(cntB[(b * VRD + f0) * 16], CAP);
                int b1 = min(cntB[(b * VRD + f1) * 16], CAP);
                int NB = b0 + b1;
                int chunk = (NB + 255) >> 8;
                int beg = tid * chunk;
                int end = min(beg + chunk, NB);
                for (int t = beg; t < end; t++) {
                    int o = (t < b0) ? (base0 + t) : (base1 + (t - b0));
                    float2 rv = recB[o];
                    int rm = __float_as_int(rv.x);
                    float px, py, pz;
                    pix2pos(rm % WW, rm / WW, rv.y, ca, sa, foc, px, py, pz);
                    float wy = 1.0f - fabsf(py - fs);
                    if (wy <= 0.0f) continue;
                    float fx = floorf(px), fz = floorf(pz);
                    int k2 = ((int)fx << 7) | (int)fz;
                    if (k2 != key) {
                        flushO();
                        key = k2;
                        a00 = a01 = a10 = a11 = 0.0f;
                    }
                    float wx0 = 1.0f - fabsf(px - fx);
                    float wx1 = 1.0f - fabsf(px - (fx + 1.0f));
                    float wz0 = 1.0f - fabsf(pz - fz);
                    float wz1 = 1.0f - fabsf(pz - (fz + 1.0f));
                    float wxy0 = wy * wx0, wxy1 = wy * wx1;
                    a00 += wxy0 * wz0; a01 += wxy0 * wz1;
                    a10 += wxy1 * wz0; a11 += wxy1 * wz1;
                }
                flushO();
            }
        }
    }
    __syncthreads();

    if (g < 8) {
        for (int i = tid; i < VRD * 2; i += 256) {
            int x = i >> 1, c = i & 1;
            float ssum = 0.0f;
            #pragma unroll 8
            for (int z = 0; z < 40; z++) ssum += rintf(acc[(z * VRD + x) * 2 + c]);
            maps[((size_t)(b * 18 + 2 + 2 * g + c) * VRD + s) * VRD + x] =
                fminf(fmaxf(ssum * 0.2f, 0.0f), 1.0f);
        }
    } else {
        for (int x = tid; x < VRD; x += 256) {
            float s_all = 0.0f, s_agg = 0.0f;
            #pragma unroll 8
            for (int z = 0; z < ZHD; z++) {
                float r = rintf(acc[z * VRD + x]);
                s_all += r;
                if (z >= MINZ && z < MAXZ) s_agg += r;
            }
            float fm = fminf(fmaxf(s_agg, 0.0f), 1.0f);
            float fe = fminf(fmaxf(s_all, 0.0f), 1.0f);
            maps[((size_t)(b * 18 + 0) * VRD + s) * VRD + x] = fm;
            maps[((size_t)(b * 18 + 1) * VRD + s) * VRD + x] = fe;
            out0[((size_t)b * VRD + s) * VRD + x] = fm;
        }
    }
}

__device__ __forceinline__ void pose_params(const float* __restrict__ pose_obs,
                                            const float* __restrict__ poses_last,
                                            int b, float& ct, float& st,
                                            float& stx, float& sty) {
    const float DEG = 57.29577951308232f;
    float o  = poses_last[b*3+2] / DEG;
    float so = sinf(o), co = cosf(o);
    float yy = poses_last[b*3+1] + pose_obs[b*3+0]*so + pose_obs[b*3+1]*co;
    float xx = poses_last[b*3+0] + pose_obs[b*3+0]*co - pose_obs[b*3+1]*so;
    float tt = poses_last[b*3+2] + pose_obs[b*3+2]*DEG;
    tt = fmodf(tt - 180.0f, 360.0f) + 180.0f;
    tt = fmodf(tt + 180.0f, 360.0f) - 180.0f;
    stx = -((xx*100.0f/5.0f) - 240.0f) / 240.0f;
    sty = -((yy*100.0f/5.0f) - 240.0f) / 240.0f;
    float t = (90.0f - tt) * 0.017453292519943295f;
    ct = cosf(t); st = sinf(t);
}

__global__ __launch_bounds__(64) void pose_kernel(const float* __restrict__ pose_obs,
                                                  const float* __restrict__ poses_last,
                                                  float* __restrict__ out) {
    int b = threadIdx.x;
    if (b >= BS) return;
    const float DEG = 57.29577951308232f;
    float o  = poses_last[b*3+2] / DEG;
    float so = sinf(o), co = cosf(o);
    float yy = poses_last[b*3+1] + pose_obs[b*3+0]*so + pose_obs[b*3+1]*co;
    float xx = poses_last[b*3+0] + pose_obs[b*3+0]*co - pose_obs[b*3+1]*so;
    float tt = poses_last[b*3+2] + pose_obs[b*3+2]*DEG;
    tt = fmodf(tt - 180.0f, 360.0f) + 180.0f;
    tt = fmodf(tt + 180.0f, 360.0f) - 180.0f;
    out[OFF2 + b*3+0] = xx; out[OFF2 + b*3+1] = yy; out[OFF2 + b*3+2] = tt;
    out[OFF3 + b*3+0] = xx; out[OFF3 + b*3+1] = yy; out[OFF3 + b*3+2] = tt;
}

__global__ __launch_bounds__(256) void rotate_kernel(const float* __restrict__ maps,
                                                     const float* __restrict__ pose_obs,
                                                     const float* __restrict__ poses_last,
                                                     float* __restrict__ rot) {
    int idx = blockIdx.x * blockDim.x + threadIdx.x;
    if (idx >= BS * MM * MM) return;
    int b   = idx / (MM * MM);
    int rem = idx % (MM * MM);
    int y   = rem / MM;
    int x   = rem % MM;
    float ct, st, stx, sty;
    pose_params(pose_obs, poses_last, b, ct, st, stx, sty);
    float Xg = -1.0f + (float)x * (2.0f / 479.0f);
    float Yg = -1.0f + (float)y * (2.0f / 479.0f);
    float gx = ct * Xg - st * Yg;
    float gy = st * Xg + ct * Yg;
    float xf = (gx + 1.0f) * 0.5f * 479.0f;
    float yf = (gy + 1.0f) * 0.5f * 479.0f;
    float x0 = floorf(xf), y0 = floorf(yf);
    float fx = xf - x0, fy = yf - y0;
    float cw[4] = {(1.0f - fx) * (1.0f - fy), fx * (1.0f - fy),
                   (1.0f - fx) * fy,          fx * fy};
    float cx[4] = {x0, x0 + 1.0f, x0, x0 + 1.0f};
    float cy[4] = {y0, y0, y0 + 1.0f, y0 + 1.0f};
    float acc[18];
    #pragma unroll
    for (int m = 0; m < 18; m++) acc[m] = 0.0f;
    #pragma unroll
    for (int k = 0; k < 4; k++) {
        float fxk = cx[k], fyk = cy[k];
        if (!(fxk >= 0.0f && fxk <= 479.0f && fyk >= 0.0f && fyk <= 479.0f)) continue;
        int ix = (int)fxk, iy = (int)fyk;
        if (iy < 240 || iy >= 340 || ix < 190 || ix >= 290) continue;
        int mi = iy - 240, mj = ix - 190;
        float w = cw[k];
        const float* mp = maps + (size_t)b * 18 * VRD * VRD + mi * VRD + mj;
        #pragma unroll
        for (int m = 0; m < 18; m++) acc[m] += w * mp[(size_t)m * VRD * VRD];
    }
    size_t obase = ((size_t)b * CHN) * MM * MM + (size_t)y * MM + x;
    rot[obase + (size_t)0 * MM * MM] = acc[0];
    rot[obase + (size_t)1 * MM * MM] = acc[1];
    rot[obase + (size_t)2 * MM * MM] = 0.0f;
    rot[obase + (size_t)3 * MM * MM] = 0.0f;
    #pragma unroll
    for (int m = 2; m < 18; m++)
        rot[obase + (size_t)(m + 2) * MM * MM] = acc[m];
}

__global__ __launch_bounds__(256) void translate_kernel(const float* __restrict__ rot,
                                                        const float* __restrict__ pose_obs,
                                                        const float* __restrict__ poses_last,
                                                        float* __restrict__ tr) {
    int idx = blockIdx.x * blockDim.x + threadIdx.x;
    if (idx >= BS * MM * MM) return;
    int b   = idx / (MM * MM);
    int rem = idx % (MM * MM);
    int y   = rem / MM;
    int x   = rem % MM;
    float ct, st, stx, sty;
    pose_params(pose_obs, poses_last, b, ct, st, stx, sty);
    float Xg = -1.0f + (float)x * (2.0f / 479.0f);
    float Yg = -1.0f + (float)y * (2.0f / 479.0f);
    float xf = (Xg + stx + 1.0f) * 0.5f * 479.0f;
    float yf = (Yg + sty + 1.0f) * 0.5f * 479.0f;
    float x0 = floorf(xf), y0 = floorf(yf);
    float fx = xf - x0, fy = yf - y0;
    float cw[4] = {(1.0f - fx) * (1.0f - fy), fx * (1.0f - fy),
                   (1.0f - fx) * fy,          fx * fy};
    float cxs[4] = {x0, x0 + 1.0f, x0, x0 + 1.0f};
    float cys[4] = {y0, y0, y0 + 1.0f, y0 + 1.0f};
    bool vk[4]; int offk[4];
    #pragma unroll
    for (int k = 0; k < 4; k++) {
        vk[k] = (cxs[k] >= 0.0f && cxs[k] <= 479.0f && cys[k] >= 0.0f && cys[k] <= 479.0f);
        offk[k] = vk[k] ? ((int)cys[k] * MM + (int)cxs[k]) : 0;
    }
    #pragma unroll
    for (int c = 0; c < CHN; c++) {
        const float* rp = rot + ((size_t)b * CHN + c) * MM * MM;
        float v = 0.0f;
        #pragma unroll
        for (int k = 0; k < 4; k++)
            if (vk[k]) v += cw[k] * rp[offk[k]];
        tr[((size_t)b * CHN + c) * MM * MM + (size_t)y * MM + x] = v;
    }
}

__global__ __launch_bounds__(256) void max_kernel(const float* __restrict__ maps_last,
                                                  const float* __restrict__ tr,
                                                  float* __restrict__ mp) {
    int i = blockIdx.x * blockDim.x + threadIdx.x;
    int n4 = BS * CHN * MM * MM / 4;
    if (i >= n4) return;
    float4 a = ((const float4*)maps_last)[i];
    float4 t = ((const float4*)tr)[i];
    float4 r;
    r.x = fmaxf(a.x, t.x);
    r.y = fmaxf(a.y, t.y);
    r.z = fmaxf(a.z, t.z);
    r.w = fmaxf(a.w, t.w);
    ((float4*)mp)[i] = r;
}

extern "C" void kernel_launch(void* const* d_in, const int* in_sizes, int n_in,
                              void* d_out, int out_size, void* d_ws, size_t ws_size,
                              hipStream_t stream) {
    const float* obs         = (const float*)d_in[0];
    const float* pose_obs    = (const float*)d_in[1];
    const float* maps_last   = (const float*)d_in[2];
    const float* poses_last  = (const float*)d_in[3];
    const float* view_angles = (const float*)d_in[4];
    float* out = (float*)d_out;

    float*  sem   = out + OFFSEM;
    float*  gpx   = out + OFFGEO;
    float*  gpy   = out + OFFGEO + SLOTS;
    float*  gpz   = out + OFFGEO + 2 * SLOTS;
    float2* recB  = (float2*)(out + OFFRB);
    float*  maps  = out + OFFMAP;
    int*    cntA  = (int*)(out + OFFCNT);
    int*    cntB  = cntA + 6400;

    hipMemsetAsync(cntA, 0, 12800 * sizeof(int), stream);

    const float foc = (float)(320.0 / tan(39.5 * M_PI / 180.0));

    int npix = BS * NPX;
    bin_kernel<<<(npix + 255) / 256, 256, 0, stream>>>(obs, view_angles, cntA, cntB,
                                                       gpx, gpy, gpz, sem, recB, foc);

    // 4 batches x 9 groups (8 sem pairs + occ) x 100 slices, batch-major
    slice_kernel<<<dim3(VRD * BS * 9), 256, 0, stream>>>(cntA, cntB, gpx, gpy, gpz,
                                                         sem, recB, view_angles,
                                                         maps, out + OFF0, foc);

    pose_kernel<<<1, 64, 0, stream>>>(pose_obs, poses_last, out);

    int nmap = BS * MM * MM;
    rotate_kernel<<<(nmap + 255) / 256, 256, 0, stream>>>(maps, pose_obs, poses_last,
                                                          out + OFF1);
    translate_kernel<<<(nmap + 255) / 256, 256, 0, stream>>>(out + OFF1, pose_obs,
                                                             poses_last, out + OFF4);
    int n4 = BS * CHN * MM * MM / 4;
    max_kernel<<<(n4 + 255) / 256, 256, 0, stream>>>(maps_last, out + OFF4, out + OFF1);
}